// Round 4
// baseline (566.699 us; speedup 1.0000x reference)
//
#include <hip/hip_runtime.h>

typedef unsigned short u16;
typedef unsigned int u32;
typedef short short8 __attribute__((ext_vector_type(8)));
typedef float f32x4 __attribute__((ext_vector_type(4)));

// ---------- helpers ----------
__device__ __forceinline__ u16 f2b(float x){
  union{float f; unsigned u;} v; v.f = x;
  unsigned r = (v.u + 0x7FFFu + ((v.u >> 16) & 1u)) >> 16;
  return (u16)r;
}
__device__ __forceinline__ float b2f(u16 h){
  union{unsigned u; float f;} v; v.u = ((unsigned)h) << 16; return v.f;
}
__device__ __forceinline__ float sigm(float x){ return 1.0f/(1.0f + __expf(-x)); }
__device__ __forceinline__ float tanh_f(float x){ return 1.0f - 2.0f/(1.0f + __expf(2.0f*x)); }

// LDS-only barrier: wait for DS ops, NOT for outstanding global loads/stores.
// Safe here: global stores in the loop are never re-read in-kernel; global loads
// are guarded by compiler-inserted vmcnt waits before their uses.
#define BAR_LDS() asm volatile("s_waitcnt lgkmcnt(0)\n\ts_barrier" ::: "memory")

// ---------- prep: Wcomb, bias, WhhB hi/lo (bf16 padded), W1 repack, hbt pad zero ----------
__global__ void prep_kernel(const float* __restrict__ Wih_f, const float* __restrict__ Whh_f,
   const float* __restrict__ bih_f, const float* __restrict__ bhh_f,
   const float* __restrict__ Wih_b, const float* __restrict__ Whh_b,
   const float* __restrict__ bih_b, const float* __restrict__ bhh_b,
   const float* __restrict__ W1,
   u16* __restrict__ wc, float* __restrict__ biasC,
   u16* __restrict__ whhH, u16* __restrict__ whhL,
   u16* __restrict__ w1b, u16* __restrict__ hbt)
{
  int id = blockIdx.x*256 + threadIdx.x;
  const int N1 = 832*128;     // wc  [n][k]
  const int N2 = 800;         // biasC
  const int N3 = 2*448*128;   // whh hi/lo [d][p(448)][k(128)]
  const int N4 = 672*320;     // w1b  (id = k*320+n)
  const int N5 = 32768*24;    // hbt pad cols 200..223
  if (id < N1){
    int n = id >> 7, k = id & 127;
    float v = 0.f;
    if (k < 100){
      if (n < 400) v = Wih_f[n*100+k];
      else if (n < 800) v = Wih_b[(n-400)*100+k];
    }
    wc[id] = f2b(v);
    return;
  }
  id -= N1;
  if (id < N2){
    biasC[id] = (id < 400) ? (bih_f[id]+bhh_f[id]) : (bih_b[id-400]+bhh_b[id-400]);
    return;
  }
  id -= N2;
  if (id < N3){
    int d = id / 57344; int rem = id - d*57344;
    int p = rem >> 7, k = rem & 127;
    int gg = p / 112; int j = p - gg*112;
    float v = 0.f;
    if (j < 100 && k < 100){
      const float* W = d ? Whh_b : Whh_f;
      v = W[(gg*100 + j)*100 + k];
    }
    u16 hi = f2b(v);
    whhH[id] = hi;
    whhL[id] = f2b(v - b2f(hi));
    return;
  }
  id -= N3;
  if (id < N4){
    int k = id / 320; int n = id - k*320;
    int seg = k / 224; int wwk = k - seg*224;
    float v = 0.f;
    if (n < 300 && wwk < 200) v = W1[(seg*200 + wwk)*300 + n];
    w1b[n*672 + k] = f2b(v);
    return;
  }
  id -= N4;
  if (id < N5){
    int p = id / 24; int k = id - p*24;
    hbt[p*224 + 200 + k] = 0;
  }
}

// ---------- GEMM1: pre-activations (emb-gathered A) -> inpP in MFMA C-layout ----------
// M=32768 (p=b*128+t), N=832 (pad of 800), K=128 (pad of 100)
// inpP layout: [g(32)][t(128)][w(7)][gg(4)][lane(64)][r(4)]  bf16
__global__ __launch_bounds__(256) void gemm1_kernel(const int* __restrict__ x,
    const float* __restrict__ emb, const u16* __restrict__ wc,
    const float* __restrict__ biasC, u16* __restrict__ inpP)
{
  __shared__ __align__(16) u16 As[64*136];
  __shared__ __align__(16) u16 Bs[64*136];
  const int m0 = blockIdx.x*64, n0 = blockIdx.y*64;
  const int tid = threadIdx.x;
  // stage A: gather emb rows, convert to bf16, pad k to 128
  {
    int row = tid >> 2, kq = tid & 3;
    const float* er = emb + (long long)x[m0+row]*100;
    #pragma unroll
    for (int kk=0;kk<8;kk++){
      int k = kq*32 + kk*4;
      float4 v = make_float4(0.f,0.f,0.f,0.f);
      if (k < 100) v = *(const float4*)&er[k];
      ushort4 s; s.x=f2b(v.x); s.y=f2b(v.y); s.z=f2b(v.z); s.w=f2b(v.w);
      *(ushort4*)&As[row*136 + k] = s;
    }
  }
  #pragma unroll
  for (int i=0;i<4;i++){
    int f = i*256 + tid;
    int row = f >> 4, c8 = f & 15;
    *(uint4*)&Bs[row*136 + c8*8] = *(const uint4*)&wc[(n0+row)*128 + c8*8];
  }
  __syncthreads();
  const int w = tid >> 6, lane = tid & 63, col = lane & 15, quad = lane >> 4;
  f32x4 acc[4];
  #pragma unroll
  for (int nt=0;nt<4;nt++) acc[nt] = (f32x4){0.f,0.f,0.f,0.f};
  #pragma unroll
  for (int kc=0;kc<4;kc++){
    short8 af = *(const short8*)&As[(w*16+col)*136 + kc*32 + quad*8];
    #pragma unroll
    for (int nt=0;nt<4;nt++){
      short8 bfrag = *(const short8*)&Bs[(nt*16+col)*136 + kc*32 + quad*8];
      acc[nt] = __builtin_amdgcn_mfma_f32_16x16x32_bf16(af, bfrag, acc[nt], 0, 0, 0);
    }
  }
  // epilogue: write to inpP permuted layout
  const int mrow0 = m0 + w*16 + quad*4;       // +r -> M row
  const int b = mrow0 >> 7, t0 = mrow0 & 127; // r increments t only
  const int ghi = b >> 4, m16 = b & 15;
  const int q2 = m16 >> 2, r2 = m16 & 3;
  #pragma unroll
  for (int nt=0;nt<4;nt++){
    int n = n0 + nt*16 + col;
    if (n < 800){
      float bs = biasC[n];
      int dir = (n >= 400) ? 1 : 0;
      int gi = n - dir*400;
      int gg = gi / 100;
      int j = gi - gg*100;
      int wL = j >> 4, colL = j & 15;
      int g = dir*16 + ghi;
      size_t base = (((size_t)(g*128 + t0)*7 + wL)*4 + gg)*256 + (q2*16 + colL)*4 + r2;
      #pragma unroll
      for (int r=0;r<4;r++){
        inpP[base + (size_t)r*7168] = f2b(acc[nt][r] + bs);
      }
    }
  }
}

// ---------- LSTM recurrence: compensated bf16 MFMA, 32 blocks x 448 thr ----------
// wave w owns padded-gate tiles {gg*7+w} => lane holds i,f,g,o for (chain=4q+r, j=16w+col)
// h and Whh kept as hi+lo bf16 pairs; acc = ah*bh + al*bh + ah*bl (12 indep accumulators)
__global__ __launch_bounds__(448, 2) void lstm_kernel(const u16* __restrict__ inpP,
    const u16* __restrict__ whhH, const u16* __restrict__ whhL, u16* __restrict__ hbt)
{
  __shared__ __align__(16) u16 hs[2][2][16][136];   // [buf][hi/lo][chain m][k pad 100->136]
  const int g = blockIdx.x;
  const int dir = g >> 4, gh = g & 15;
  const int tid = threadIdx.x;
  const int w = tid >> 6, lane = tid & 63, col = lane & 15, q = lane >> 4;
  // zero both buffers, both planes (h0 = 0, and k-pad stays 0 forever)
  for (int i = tid; i < 4352; i += 448) ((u32*)hs)[i] = 0u;
  // load Whh B-fragments (hi+lo) into registers (resident whole kernel)
  short8 bh[4][4], bl[4][4];   // [gg][kc]
  {
    int p = w*16 + col;
    #pragma unroll
    for (int gg=0;gg<4;gg++)
      #pragma unroll
      for (int kc=0;kc<4;kc++){
        size_t off = (size_t)(dir*448 + gg*112 + p)*128 + kc*32 + q*8;
        bh[gg][kc] = *(const short8*)&whhH[off];
        bl[gg][kc] = *(const short8*)&whhL[off];
      }
  }
  float c[4] = {0.f,0.f,0.f,0.f};
  const int j = w*16 + col;
  const bool wr_en = ((col & 1) == 0) && (j < 100);
  const u16* ip_lane = inpP + (size_t)g*128*7168 + w*1024 + lane*4;
  // per-r precomputed bases
  u16* hbr[4];
  int hswr[4];
  #pragma unroll
  for (int r=0;r<4;r++){
    hbr[r] = hbt + (size_t)(gh*16 + 4*q + r)*28672 + dir*100 + j;
    hswr[r] = (4*q + r)*68 + w*8 + (col>>1);
  }
  const int hsrd = col*68 + q*4;   // u32 word offset within a plane for A-frag reads
  int cur = 0;
  // prefetch t0
  int t = dir ? 127 : 0;
  uint2 pre[4];
  __syncthreads();
  #pragma unroll
  for (int gg=0;gg<4;gg++) pre[gg] = *(const uint2*)&ip_lane[(size_t)t*7168 + gg*256];

  for (int step=0; step<128; step++){
    t = dir ? (127-step) : step;
    // grab current inp regs, then immediately issue prefetch for next step
    uint2 cp[4];
    #pragma unroll
    for (int gg=0;gg<4;gg++) cp[gg] = pre[gg];
    if (step < 127){
      int tn = dir ? (126-step) : (step+1);
      #pragma unroll
      for (int gg=0;gg<4;gg++) pre[gg] = *(const uint2*)&ip_lane[(size_t)tn*7168 + gg*256];
    }
    // A fragments (hi+lo planes) from hs[cur]
    short8 ah[4], al[4];
    const u32* hb32 = (const u32*)hs + cur*2176 + hsrd;
    #pragma unroll
    for (int kc=0;kc<4;kc++){
      ah[kc] = *(const short8*)(hb32 + kc*16);
      al[kc] = *(const short8*)(hb32 + 1088 + kc*16);
    }
    // 12 independent accumulators: depth-4 chains, 12-way ILP
    f32x4 aH[4], aM[4], aL[4];
    #pragma unroll
    for (int gg=0;gg<4;gg++){
      aH[gg] = (f32x4){0.f,0.f,0.f,0.f};
      aM[gg] = (f32x4){0.f,0.f,0.f,0.f};
      aL[gg] = (f32x4){0.f,0.f,0.f,0.f};
    }
    #pragma unroll
    for (int kc=0;kc<4;kc++)
      #pragma unroll
      for (int gg=0;gg<4;gg++)
        aH[gg] = __builtin_amdgcn_mfma_f32_16x16x32_bf16(ah[kc], bh[gg][kc], aH[gg], 0, 0, 0);
    #pragma unroll
    for (int kc=0;kc<4;kc++)
      #pragma unroll
      for (int gg=0;gg<4;gg++)
        aM[gg] = __builtin_amdgcn_mfma_f32_16x16x32_bf16(al[kc], bh[gg][kc], aM[gg], 0, 0, 0);
    #pragma unroll
    for (int kc=0;kc<4;kc++)
      #pragma unroll
      for (int gg=0;gg<4;gg++)
        aL[gg] = __builtin_amdgcn_mfma_f32_16x16x32_bf16(ah[kc], bl[gg][kc], aL[gg], 0, 0, 0);
    // unpack pre-activation addends
    float pr[4][4];
    #pragma unroll
    for (int gg=0;gg<4;gg++){
      union{u32 u; float f;} v;
      v.u = cp[gg].x << 16;         pr[gg][0] = v.f;
      v.u = cp[gg].x & 0xffff0000u; pr[gg][1] = v.f;
      v.u = cp[gg].y << 16;         pr[gg][2] = v.f;
      v.u = cp[gg].y & 0xffff0000u; pr[gg][3] = v.f;
    }
    // register-local gate activation + cell update
    float h[4];
    #pragma unroll
    for (int r=0;r<4;r++){
      float xi = aH[0][r] + (aM[0][r] + aL[0][r]) + pr[0][r];
      float xf = aH[1][r] + (aM[1][r] + aL[1][r]) + pr[1][r];
      float xg = aH[2][r] + (aM[2][r] + aL[2][r]) + pr[2][r];
      float xo = aH[3][r] + (aM[3][r] + aL[3][r]) + pr[3][r];
      float fi = sigm(xi), ff = sigm(xf), gv = tanh_f(xg), fo = sigm(xo);
      c[r] = ff*c[r] + fi*gv;
      h[r] = fo * tanh_f(c[r]);
    }
    // split h into hi+lo, pack pairs (even col holds j, j+1), write LDS(next) + global hbt
    u32* hw32 = (u32*)hs + (cur^1)*2176;
    #pragma unroll
    for (int r=0;r<4;r++){
      u16 hb = f2b(h[r]);
      float lo = h[r] - b2f(hb);
      u32 my = (u32)hb | ((u32)f2b(lo) << 16);   // [hi | lo]
      u32 other = __shfl_xor((int)my, 1, 64);
      if (wr_en){
        u32 pk_hi = (my & 0xffffu) | ((other & 0xffffu) << 16);
        u32 pk_lo = (my >> 16) | (other & 0xffff0000u);
        hw32[hswr[r]] = pk_hi;
        hw32[1088 + hswr[r]] = pk_lo;
        *(u32*)(hbr[r] + (size_t)t*224) = pk_hi;
      }
    }
    BAR_LDS();
    cur ^= 1;
  }
}

// ---------- MLP: gathered bf16 MFMA GEMM + tanh + W2 + softmax fused ----------
__global__ __launch_bounds__(512) void mlp_kernel(const u16* __restrict__ hbt,
    const u16* __restrict__ w1b, const int* __restrict__ paths,
    const float* __restrict__ b1, const float* __restrict__ W2,
    const float* __restrict__ b2, float* __restrict__ out)
{
  __shared__ __align__(16) u16 As[128*40];
  __shared__ __align__(16) u16 Bs[320*40];
  const int m0 = blockIdx.x*128;
  const int tid = threadIdx.x;
  const int arow = tid >> 2, ac8 = tid & 3;
  const int am = m0 + arow;
  const int ab = am / 255;
  const int w = tid >> 6, lane = tid & 63, col = lane & 15, quad = lane >> 4;
  f32x4 acc[20];
  #pragma unroll
  for (int nt=0;nt<20;nt++) acc[nt] = (f32x4){0.f,0.f,0.f,0.f};
  for (int kc=0;kc<21;kc++){
    __syncthreads();
    for (int f = tid; f < 1280; f += 512){
      int br = f >> 2, bc = f & 3;
      *(uint4*)&Bs[br*40 + bc*8] = *(const uint4*)&w1b[br*672 + kc*32 + bc*8];
    }
    int seg = (kc >= 14) ? 2 : (kc >= 7 ? 1 : 0);
    int ko = kc - seg*7;
    int it = paths[am*3 + seg];
    uint4 v = make_uint4(0u,0u,0u,0u);
    if (it >= 0){
      int tt = it > 127 ? 127 : it;
      v = *(const uint4*)&hbt[(ab*128 + tt)*224 + ko*32 + ac8*8];
    }
    *(uint4*)&As[arow*40 + ac8*8] = v;
    __syncthreads();
    short8 af = *(const short8*)&As[(w*16+col)*40 + quad*8];
    #pragma unroll
    for (int nt=0;nt<20;nt++){
      short8 bfrag = *(const short8*)&Bs[(nt*16+col)*40 + quad*8];
      acc[nt] = __builtin_amdgcn_mfma_f32_16x16x32_bf16(af, bfrag, acc[nt], 0, 0, 0);
    }
  }
  float pz[4][3];
  #pragma unroll
  for (int r=0;r<4;r++){ pz[r][0]=0.f; pz[r][1]=0.f; pz[r][2]=0.f; }
  #pragma unroll
  for (int nt=0;nt<20;nt++){
    int n = nt*16 + col;
    if (n < 300){
      float bb = b1[n];
      float w20 = W2[n*3+0], w21 = W2[n*3+1], w22 = W2[n*3+2];
      #pragma unroll
      for (int r=0;r<4;r++){
        float hdn = tanh_f(acc[nt][r] + bb);
        pz[r][0] = fmaf(hdn, w20, pz[r][0]);
        pz[r][1] = fmaf(hdn, w21, pz[r][1]);
        pz[r][2] = fmaf(hdn, w22, pz[r][2]);
      }
    }
  }
  #pragma unroll
  for (int off=1; off<16; off<<=1){
    #pragma unroll
    for (int r=0;r<4;r++){
      pz[r][0] += __shfl_xor(pz[r][0], off, 64);
      pz[r][1] += __shfl_xor(pz[r][1], off, 64);
      pz[r][2] += __shfl_xor(pz[r][2], off, 64);
    }
  }
  float c0 = b2[0], c1 = b2[1], c2 = b2[2];
  #pragma unroll
  for (int r=0;r<4;r++){
    float z0 = pz[r][0]+c0, z1 = pz[r][1]+c1, z2 = pz[r][2]+c2;
    float mx = fmaxf(z0, fmaxf(z1, z2));
    float e0 = __expf(z0-mx), e1 = __expf(z1-mx), e2 = __expf(z2-mx);
    float inv = 1.0f/(e0+e1+e2);
    if (col < 3){
      float pv = (col==0 ? e0 : (col==1 ? e1 : e2)) * inv;
      out[(m0 + w*16 + quad*4 + r)*3 + col] = pv;
    }
  }
}

// ---------- launch ----------
extern "C" void kernel_launch(void* const* d_in, const int* in_sizes, int n_in,
                              void* d_out, int out_size, void* d_ws, size_t ws_size,
                              hipStream_t stream)
{
  const int*   x     = (const int*)  d_in[0];
  const int*   paths = (const int*)  d_in[1];
  const float* emb   = (const float*)d_in[2];
  const float* Wih_f = (const float*)d_in[3];
  const float* Whh_f = (const float*)d_in[4];
  const float* bih_f = (const float*)d_in[5];
  const float* bhh_f = (const float*)d_in[6];
  const float* Wih_b = (const float*)d_in[7];
  const float* Whh_b = (const float*)d_in[8];
  const float* bih_b = (const float*)d_in[9];
  const float* bhh_b = (const float*)d_in[10];
  const float* W1    = (const float*)d_in[11];
  const float* b1    = (const float*)d_in[12];
  const float* W2    = (const float*)d_in[13];
  const float* b2    = (const float*)d_in[14];
  float* out = (float*)d_out;

  char* ws = (char*)d_ws;
  u16*   wc    = (u16*)  (ws + 0);           //   212,992 B
  float* biasC = (float*)(ws + 212992);      //     3,200 B
  u16*   whhH  = (u16*)  (ws + 216192);      //   229,376 B
  u16*   whhL  = (u16*)  (ws + 445568);      //   229,376 B
  u16*   w1b   = (u16*)  (ws + 674944);      //   430,080 B
  u16*   inpP  = (u16*)  (ws + 1105024);     // 58,720,256 B
  u16*   hbt   = (u16*)  (ws + 59825280);    // 14,680,064 B  (total 74,505,344)

  const int prep_total = 832*128 + 800 + 2*448*128 + 672*320 + 32768*24;
  prep_kernel<<<(prep_total + 255)/256, 256, 0, stream>>>(
      Wih_f, Whh_f, bih_f, bhh_f, Wih_b, Whh_b, bih_b, bhh_b, W1,
      wc, biasC, whhH, whhL, w1b, hbt);
  gemm1_kernel<<<dim3(512, 13), 256, 0, stream>>>(x, emb, wc, biasC, inpP);
  lstm_kernel<<<32, 448, 0, stream>>>(inpP, whhH, whhL, hbt);
  mlp_kernel<<<510, 512, 0, stream>>>(hbt, w1b, paths, b1, W2, b2, out);
}

// Round 5
// 496.098 us; speedup vs baseline: 1.1423x; 1.1423x over previous
//
#include <hip/hip_runtime.h>

typedef unsigned short u16;
typedef unsigned int u32;
typedef short short8 __attribute__((ext_vector_type(8)));
typedef float f32x4 __attribute__((ext_vector_type(4)));

// ---------- helpers ----------
__device__ __forceinline__ u16 f2b(float x){
  union{float f; unsigned u;} v; v.f = x;
  unsigned r = (v.u + 0x7FFFu + ((v.u >> 16) & 1u)) >> 16;
  return (u16)r;
}
__device__ __forceinline__ float b2f(u16 h){
  union{unsigned u; float f;} v; v.u = ((unsigned)h) << 16; return v.f;
}
__device__ __forceinline__ float sigm(float x){ return 1.0f/(1.0f + __expf(-x)); }
__device__ __forceinline__ float tanh_f(float x){ return 1.0f - 2.0f/(1.0f + __expf(2.0f*x)); }

// LDS-only barrier: wait for DS ops, NOT for outstanding global loads/stores.
// Safe: in-loop global stores are never re-read in-kernel; global loads are
// guarded by compiler-inserted vmcnt waits before their uses.
#define BAR_LDS() asm volatile("s_waitcnt lgkmcnt(0)\n\ts_barrier" ::: "memory")

// ---------- prep: Wcomb, bias, whhT (gate-interleaved), W1 repack, hbt pad ----------
__global__ void prep_kernel(const float* __restrict__ Wih_f, const float* __restrict__ Whh_f,
   const float* __restrict__ bih_f, const float* __restrict__ bhh_f,
   const float* __restrict__ Wih_b, const float* __restrict__ Whh_b,
   const float* __restrict__ bih_b, const float* __restrict__ bhh_b,
   const float* __restrict__ W1,
   u16* __restrict__ wc, float* __restrict__ biasC,
   float* __restrict__ whhT, u16* __restrict__ w1b, u16* __restrict__ hbt)
{
  int id = blockIdx.x*256 + threadIdx.x;
  const int N1 = 832*128;     // wc  [n][k]
  const int N2 = 800;         // biasC
  const int N3 = 80000;       // whhT [d][k(100)][t(400)]  t = u*4+gg (gate-interleaved)
  const int N4 = 672*320;     // w1b  (id = k*320+n)
  const int N5 = 32768*24;    // hbt pad cols 200..223
  if (id < N1){
    int n = id >> 7, k = id & 127;
    float v = 0.f;
    if (k < 100){
      if (n < 400) v = Wih_f[n*100+k];
      else if (n < 800) v = Wih_b[(n-400)*100+k];
    }
    wc[id] = f2b(v);
    return;
  }
  id -= N1;
  if (id < N2){
    biasC[id] = (id < 400) ? (bih_f[id]+bhh_f[id]) : (bih_b[id-400]+bhh_b[id-400]);
    return;
  }
  id -= N2;
  if (id < N3){
    int d = id / 40000; int rem = id - d*40000;
    int k = rem / 400; int t = rem - k*400;
    int u = t >> 2, gg = t & 3;
    const float* W = d ? Whh_b : Whh_f;
    whhT[id] = W[(gg*100 + u)*100 + k];
    return;
  }
  id -= N3;
  if (id < N4){
    int k = id / 320; int n = id - k*320;
    int seg = k / 224; int wwk = k - seg*224;
    float v = 0.f;
    if (n < 300 && wwk < 200) v = W1[(seg*200 + wwk)*300 + n];
    w1b[n*672 + k] = f2b(v);
    return;
  }
  id -= N4;
  if (id < N5){
    int p = id / 24; int k = id - p*24;
    hbt[p*224 + 200 + k] = 0;
  }
}

// ---------- GEMM1: pre-activations (emb-gathered A) -> inp, gate-interleaved rows ----------
// M=32768 (p=b*128+t), N=832 (pad of 800), K=128 (pad of 100)
// inp layout: [d][b*128+t][400] with row index jn = unit*4 + gate
__global__ __launch_bounds__(256) void gemm1_kernel(const int* __restrict__ x,
    const float* __restrict__ emb, const u16* __restrict__ wc,
    const float* __restrict__ biasC, u16* __restrict__ inp)
{
  __shared__ __align__(16) u16 As[64*136];
  __shared__ __align__(16) u16 Bs[64*136];
  const int m0 = blockIdx.x*64, n0 = blockIdx.y*64;
  const int tid = threadIdx.x;
  // stage A: gather emb rows, convert to bf16, pad k to 128
  {
    int row = tid >> 2, kq = tid & 3;
    const float* er = emb + (long long)x[m0+row]*100;
    #pragma unroll
    for (int kk=0;kk<8;kk++){
      int k = kq*32 + kk*4;
      float4 v = make_float4(0.f,0.f,0.f,0.f);
      if (k < 100) v = *(const float4*)&er[k];
      ushort4 s; s.x=f2b(v.x); s.y=f2b(v.y); s.z=f2b(v.z); s.w=f2b(v.w);
      *(ushort4*)&As[row*136 + k] = s;
    }
  }
  #pragma unroll
  for (int i=0;i<4;i++){
    int f = i*256 + tid;
    int row = f >> 4, c8 = f & 15;
    *(uint4*)&Bs[row*136 + c8*8] = *(const uint4*)&wc[(n0+row)*128 + c8*8];
  }
  __syncthreads();
  const int w = tid >> 6, lane = tid & 63, col = lane & 15, quad = lane >> 4;
  f32x4 acc[4];
  #pragma unroll
  for (int nt=0;nt<4;nt++) acc[nt] = (f32x4){0.f,0.f,0.f,0.f};
  #pragma unroll
  for (int kc=0;kc<4;kc++){
    short8 af = *(const short8*)&As[(w*16+col)*136 + kc*32 + quad*8];
    #pragma unroll
    for (int nt=0;nt<4;nt++){
      short8 bfrag = *(const short8*)&Bs[(nt*16+col)*136 + kc*32 + quad*8];
      acc[nt] = __builtin_amdgcn_mfma_f32_16x16x32_bf16(af, bfrag, acc[nt], 0, 0, 0);
    }
  }
  const int mrow0 = m0 + w*16 + quad*4;
  #pragma unroll
  for (int nt=0;nt<4;nt++){
    int n = n0 + nt*16 + col;
    if (n < 800){
      float bs = biasC[n];
      int dir = (n >= 400) ? 1 : 0;
      int gi = n - dir*400;
      int gg = gi / 100;
      int uu = gi - gg*100;
      int jn = uu*4 + gg;
      u16* op = inp + ((size_t)(dir*32768 + mrow0))*400 + jn;
      #pragma unroll
      for (int r=0;r<4;r++) op[(size_t)r*400] = f2b(acc[nt][r] + bs);
    }
  }
}

// ---------- LSTM recurrence: fp32 VALU, gate-interleaved, 2 chains/block ----------
// 256 blocks (1/CU) x 448 thr. Thread jj<400: unit u=jj>>2, gate tg=jj&3.
// One barrier/step; h double-buffered fp32 in LDS, chains interleaved {hA,hB}.
__global__ __launch_bounds__(448) void lstm_kernel(const u16* __restrict__ inp,
    const float* __restrict__ whhT, u16* __restrict__ hbt)
{
  __shared__ __align__(16) float hs[2][208];   // [buf][2*u + chain]
  const int bid = blockIdx.x;
  const int dir = bid >> 7, i2 = bid & 127;
  const int b0 = i2*2;
  const int jj = threadIdx.x;
  const int tg = jj & 3, u = jj >> 2;
  for (int k = jj; k < 416; k += 448) ((float*)hs)[k] = 0.f;
  float whh[100];
  const bool act = (jj < 400);
  if (act){
    const float* wp = whhT + dir*40000 + jj;
    #pragma unroll
    for (int k=0;k<100;k++) whh[k] = wp[k*400];
  }
  const u16* ip0 = inp + ((size_t)(dir*32768 + b0*128))*400 + jj;
  const u16* ip1 = ip0 + 51200;
  u16* hb0 = hbt + (size_t)(b0*128)*224 + dir*100 + u;
  u16* hb1 = hb0 + 28672;
  float cA = 0.f, cB = 0.f;
  int cur = 0;
  __syncthreads();
  int t0 = dir ? 127 : 0;
  u16 preA = 0, preB = 0;
  if (act){ preA = ip0[(size_t)t0*400]; preB = ip1[(size_t)t0*400]; }
  for (int step=0; step<128; step++){
    int t = dir ? (127-step) : step;
    if (act){
      float pA = b2f(preA), pB = b2f(preB);
      if (step < 127){
        int tn = dir ? (126-step) : (step+1);
        preA = ip0[(size_t)tn*400];
        preB = ip1[(size_t)tn*400];
      }
      // dot(h_prev, whh_row) for both chains; h interleaved {A,B} per unit
      const float4* h4 = (const float4*)hs[cur];
      float a0=0.f, a1=0.f, d0=0.f, d1=0.f;
      #pragma unroll
      for (int kk=0;kk<50;kk+=2){
        float4 v0 = h4[kk], v1 = h4[kk+1];
        a0 = fmaf(whh[2*kk+0], v0.x, a0);  d0 = fmaf(whh[2*kk+0], v0.y, d0);
        a1 = fmaf(whh[2*kk+1], v0.z, a1);  d1 = fmaf(whh[2*kk+1], v0.w, d1);
        a0 = fmaf(whh[2*kk+2], v1.x, a0);  d0 = fmaf(whh[2*kk+2], v1.y, d0);
        a1 = fmaf(whh[2*kk+3], v1.z, a1);  d1 = fmaf(whh[2*kk+3], v1.w, d1);
      }
      float xA = pA + a0 + a1;
      float xB = pB + d0 + d1;
      // quad gate exchange: pick[m] = gate (tg^m)
      float pA1 = __shfl_xor(xA, 1, 64), pA2 = __shfl_xor(xA, 2, 64), pA3 = __shfl_xor(pA1, 2, 64);
      float pB1 = __shfl_xor(xB, 1, 64), pB2 = __shfl_xor(xB, 2, 64), pB3 = __shfl_xor(pB1, 2, 64);
      const bool s1 = (tg & 1), s2 = (tg & 2);
      float hA, hB;
      {
        float q0 = s1? pA1:xA, q1 = s1? xA:pA1, q2 = s1? pA3:pA2, q3 = s1? pA2:pA3;
        float gi = s2? q2:q0, gf = s2? q3:q1, gv = s2? q0:q2, go = s2? q1:q3;
        cA = sigm(gf)*cA + sigm(gi)*tanh_f(gv);
        hA = sigm(go)*tanh_f(cA);
      }
      {
        float q0 = s1? pB1:xB, q1 = s1? xB:pB1, q2 = s1? pB3:pB2, q3 = s1? pB2:pB3;
        float gi = s2? q2:q0, gf = s2? q3:q1, gv = s2? q0:q2, go = s2? q1:q3;
        cB = sigm(gf)*cB + sigm(gi)*tanh_f(gv);
        hB = sigm(go)*tanh_f(cB);
      }
      if (tg == 0){
        *(float2*)&hs[cur^1][2*u] = make_float2(hA, hB);
        hb0[(size_t)t*224] = f2b(hA);
        hb1[(size_t)t*224] = f2b(hB);
      }
    }
    BAR_LDS();
    cur ^= 1;
  }
}

// ---------- MLP: gathered bf16 MFMA GEMM + tanh + W2 + softmax fused ----------
__global__ __launch_bounds__(512) void mlp_kernel(const u16* __restrict__ hbt,
    const u16* __restrict__ w1b, const int* __restrict__ paths,
    const float* __restrict__ b1, const float* __restrict__ W2,
    const float* __restrict__ b2, float* __restrict__ out)
{
  __shared__ __align__(16) u16 As[128*40];
  __shared__ __align__(16) u16 Bs[320*40];
  const int m0 = blockIdx.x*128;
  const int tid = threadIdx.x;
  const int arow = tid >> 2, ac8 = tid & 3;
  const int am = m0 + arow;
  const int ab = am / 255;
  const int w = tid >> 6, lane = tid & 63, col = lane & 15, quad = lane >> 4;
  f32x4 acc[20];
  #pragma unroll
  for (int nt=0;nt<20;nt++) acc[nt] = (f32x4){0.f,0.f,0.f,0.f};
  for (int kc=0;kc<21;kc++){
    __syncthreads();
    for (int f = tid; f < 1280; f += 512){
      int br = f >> 2, bc = f & 3;
      *(uint4*)&Bs[br*40 + bc*8] = *(const uint4*)&w1b[br*672 + kc*32 + bc*8];
    }
    int seg = (kc >= 14) ? 2 : (kc >= 7 ? 1 : 0);
    int ko = kc - seg*7;
    int it = paths[am*3 + seg];
    uint4 v = make_uint4(0u,0u,0u,0u);
    if (it >= 0){
      int tt = it > 127 ? 127 : it;
      v = *(const uint4*)&hbt[(ab*128 + tt)*224 + ko*32 + ac8*8];
    }
    *(uint4*)&As[arow*40 + ac8*8] = v;
    __syncthreads();
    short8 af = *(const short8*)&As[(w*16+col)*40 + quad*8];
    #pragma unroll
    for (int nt=0;nt<20;nt++){
      short8 bfrag = *(const short8*)&Bs[(nt*16+col)*40 + quad*8];
      acc[nt] = __builtin_amdgcn_mfma_f32_16x16x32_bf16(af, bfrag, acc[nt], 0, 0, 0);
    }
  }
  float pz[4][3];
  #pragma unroll
  for (int r=0;r<4;r++){ pz[r][0]=0.f; pz[r][1]=0.f; pz[r][2]=0.f; }
  #pragma unroll
  for (int nt=0;nt<20;nt++){
    int n = nt*16 + col;
    if (n < 300){
      float bb = b1[n];
      float w20 = W2[n*3+0], w21 = W2[n*3+1], w22 = W2[n*3+2];
      #pragma unroll
      for (int r=0;r<4;r++){
        float hdn = tanh_f(acc[nt][r] + bb);
        pz[r][0] = fmaf(hdn, w20, pz[r][0]);
        pz[r][1] = fmaf(hdn, w21, pz[r][1]);
        pz[r][2] = fmaf(hdn, w22, pz[r][2]);
      }
    }
  }
  #pragma unroll
  for (int off=1; off<16; off<<=1){
    #pragma unroll
    for (int r=0;r<4;r++){
      pz[r][0] += __shfl_xor(pz[r][0], off, 64);
      pz[r][1] += __shfl_xor(pz[r][1], off, 64);
      pz[r][2] += __shfl_xor(pz[r][2], off, 64);
    }
  }
  float c0 = b2[0], c1 = b2[1], c2 = b2[2];
  #pragma unroll
  for (int r=0;r<4;r++){
    float z0 = pz[r][0]+c0, z1 = pz[r][1]+c1, z2 = pz[r][2]+c2;
    float mx = fmaxf(z0, fmaxf(z1, z2));
    float e0 = __expf(z0-mx), e1 = __expf(z1-mx), e2 = __expf(z2-mx);
    float inv = 1.0f/(e0+e1+e2);
    if (col < 3){
      float pv = (col==0 ? e0 : (col==1 ? e1 : e2)) * inv;
      out[(m0 + w*16 + quad*4 + r)*3 + col] = pv;
    }
  }
}

// ---------- launch ----------
extern "C" void kernel_launch(void* const* d_in, const int* in_sizes, int n_in,
                              void* d_out, int out_size, void* d_ws, size_t ws_size,
                              hipStream_t stream)
{
  const int*   x     = (const int*)  d_in[0];
  const int*   paths = (const int*)  d_in[1];
  const float* emb   = (const float*)d_in[2];
  const float* Wih_f = (const float*)d_in[3];
  const float* Whh_f = (const float*)d_in[4];
  const float* bih_f = (const float*)d_in[5];
  const float* bhh_f = (const float*)d_in[6];
  const float* Wih_b = (const float*)d_in[7];
  const float* Whh_b = (const float*)d_in[8];
  const float* bih_b = (const float*)d_in[9];
  const float* bhh_b = (const float*)d_in[10];
  const float* W1    = (const float*)d_in[11];
  const float* b1    = (const float*)d_in[12];
  const float* W2    = (const float*)d_in[13];
  const float* b2    = (const float*)d_in[14];
  float* out = (float*)d_out;

  char* ws = (char*)d_ws;
  u16*   wc    = (u16*)  (ws + 0);           //   212,992 B
  float* biasC = (float*)(ws + 212992);      //     3,200 B
  float* whhT  = (float*)(ws + 216192);      //   320,000 B
  u16*   w1b   = (u16*)  (ws + 536192);      //   430,080 B
  u16*   inp   = (u16*)  (ws + 966272);      // 52,428,800 B
  u16*   hbt   = (u16*)  (ws + 53395072);    // 14,680,064 B  (total 68,075,136)

  const int prep_total = 832*128 + 800 + 80000 + 672*320 + 32768*24;
  prep_kernel<<<(prep_total + 255)/256, 256, 0, stream>>>(
      Wih_f, Whh_f, bih_f, bhh_f, Wih_b, Whh_b, bih_b, bhh_b, W1,
      wc, biasC, whhT, w1b, hbt);
  gemm1_kernel<<<dim3(512, 13), 256, 0, stream>>>(x, emb, wc, biasC, inp);
  lstm_kernel<<<256, 448, 0, stream>>>(inp, whhT, hbt);
  mlp_kernel<<<510, 512, 0, stream>>>(hbt, w1b, paths, b1, W2, b2, out);
}